// Round 1
// baseline (564.984 us; speedup 1.0000x reference)
//
#include <hip/hip_runtime.h>

#define PS 7        // pool size (reference POOL = 7)
#define NC 8        // channels
#define DIM 256     // image spatial extent
#define NVOX (PS * PS * PS)              // 343
#define NROIS 64
#define NC4 2                            // float4 groups per voxel (8 ch / 4)
#define PER_ROI_ITEMS (NVOX * NC4)       // 686
#define ITEMS (NROIS * PER_ROI_ITEMS)    // 43904
#define BLOCK 256

// one thread per (roi, output-voxel, channel-half): 8x float4 gathers, 1x float4 store
__global__ __launch_bounds__(BLOCK)
void roi_pool3d_kernel(const float* __restrict__ img,
                       const int* __restrict__ rois,
                       float4* __restrict__ out) {
    const int g = blockIdx.x * BLOCK + threadIdx.x;
    if (g >= ITEMS) return;

    const int r   = g / PER_ROI_ITEMS;
    const int rem = g - r * PER_ROI_ITEMS;
    const int c4  = rem & 1;             // which half of the 8 channels
    const int vox = rem >> 1;            // 0..342
    const int pz  = vox % PS;
    const int t2  = vox / PS;
    const int py  = t2 % PS;
    const int px  = t2 / PS;

    const int* roi = rois + r * 6;
    const int x = roi[0], y = roi[1], z = roi[2];
    const int w = roi[3], h = roi[4], d = roi[5];

    // reference numerics: src = i*(size/ps); i0=floor(src); frac from
    // unclamped i0; i0c=min(i0,size-1); i1=min(i0+1,size-1)
    float srx = (float)px * ((float)w / (float)PS);
    int ix0 = (int)floorf(srx);
    float fx = srx - (float)ix0;
    int X0 = x + min(ix0, w - 1);
    int X1 = x + min(ix0 + 1, w - 1);

    float sry = (float)py * ((float)h / (float)PS);
    int iy0 = (int)floorf(sry);
    float fy = sry - (float)iy0;
    int Y0 = y + min(iy0, h - 1);
    int Y1 = y + min(iy0 + 1, h - 1);

    float srz = (float)pz * ((float)d / (float)PS);
    int iz0 = (int)floorf(srz);
    float fz = srz - (float)iz0;
    int Z0 = z + min(iz0, d - 1);
    int Z1 = z + min(iz0 + 1, d - 1);

    const int coff = c4 << 2;   // 0 or 4 floats into the 8-channel group
    #define VOX_AT(X, Y, Z) \
        (*(const float4*)(img + ((((X) * DIM + (Y)) * DIM + (Z)) * NC + coff)))
    const float4 v000 = VOX_AT(X0, Y0, Z0);
    const float4 v001 = VOX_AT(X0, Y0, Z1);
    const float4 v010 = VOX_AT(X0, Y1, Z0);
    const float4 v011 = VOX_AT(X0, Y1, Z1);
    const float4 v100 = VOX_AT(X1, Y0, Z0);
    const float4 v101 = VOX_AT(X1, Y0, Z1);
    const float4 v110 = VOX_AT(X1, Y1, Z0);
    const float4 v111 = VOX_AT(X1, Y1, Z1);
    #undef VOX_AT

    // z, then y, then x — same per-component order/arithmetic as reference:
    // a*(1-f) + b*f
    const float gz = 1.0f - fz;
    const float gy = 1.0f - fy;
    const float gx = 1.0f - fx;

    float4 res;
    {
        float c00 = v000.x * gz + v001.x * fz;
        float c01 = v010.x * gz + v011.x * fz;
        float c10 = v100.x * gz + v101.x * fz;
        float c11 = v110.x * gz + v111.x * fz;
        float c0 = c00 * gy + c01 * fy;
        float c1 = c10 * gy + c11 * fy;
        res.x = c0 * gx + c1 * fx;
    }
    {
        float c00 = v000.y * gz + v001.y * fz;
        float c01 = v010.y * gz + v011.y * fz;
        float c10 = v100.y * gz + v101.y * fz;
        float c11 = v110.y * gz + v111.y * fz;
        float c0 = c00 * gy + c01 * fy;
        float c1 = c10 * gy + c11 * fy;
        res.y = c0 * gx + c1 * fx;
    }
    {
        float c00 = v000.z * gz + v001.z * fz;
        float c01 = v010.z * gz + v011.z * fz;
        float c10 = v100.z * gz + v101.z * fz;
        float c11 = v110.z * gz + v111.z * fz;
        float c0 = c00 * gy + c01 * fy;
        float c1 = c10 * gy + c11 * fy;
        res.z = c0 * gx + c1 * fx;
    }
    {
        float c00 = v000.w * gz + v001.w * fz;
        float c01 = v010.w * gz + v011.w * fz;
        float c10 = v100.w * gz + v101.w * fz;
        float c11 = v110.w * gz + v111.w * fz;
        float c0 = c00 * gy + c01 * fy;
        float c1 = c10 * gy + c11 * fy;
        res.w = c0 * gx + c1 * fx;
    }

    // out float4 index == g by construction: ((r*NVOX + vox)*NC + c4*4)/4
    out[g] = res;
}

extern "C" void kernel_launch(void* const* d_in, const int* in_sizes, int n_in,
                              void* d_out, int out_size, void* d_ws, size_t ws_size,
                              hipStream_t stream) {
    const float* img  = (const float*)d_in[0];
    const int*   rois = (const int*)d_in[1];
    float4* out = (float4*)d_out;

    const int nblocks = (ITEMS + BLOCK - 1) / BLOCK;   // 172
    roi_pool3d_kernel<<<nblocks, BLOCK, 0, stream>>>(img, rois, out);
}